// Round 8
// baseline (190.559 us; speedup 1.0000x reference)
//
#include <hip/hip_runtime.h>
#include <stdint.h>

#define NQ   8192
#define NB   2
#define KNN  10
#define K1   11                 // top-11 incl. self (dist 0 = global min key); dropped at end
#define NTOT (NB * NQ)
#define IDXMASK 0x1FFFu

// tau kernel: per query, 11th-smallest key over a fixed 1024-point subsample (stride 8)
#define SUBS   1024
#define SSTRIDE 8
#define TW     16               // waves in tau block (1024 threads, 64 queries)
#define CKI(s, c, lane) (((s) * TW + (c)) * 64 + (lane))

// scan kernel: group of 64 queries x 4 blocks; each block scans 2048 candidates
#define HB    4                 // blocks per query-group
#define CPB   (NQ / HB)         // 2048 candidates per block
#define TILE  1024              // candidates staged in LDS per tile
#define WPB   8                 // waves per scan block (512 threads)
#define CPWT  (TILE / WPB)      // 128 candidates per wave per tile
#define CAPQ  80                // list capacity per (query, block); mean occupancy ~22
#define LSTR  81                // LDS list stride (breaks same-bank appends)

static __device__ __forceinline__ uint32_t umin32(uint32_t a, uint32_t b) { return a < b ? a : b; }
static __device__ __forceinline__ uint32_t umax32(uint32_t a, uint32_t b) { return a > b ? a : b; }

static __device__ __forceinline__ void insert11(uint32_t (&l)[K1], uint32_t key) {
#pragma unroll
    for (int s = 0; s < K1; ++s) {
        const uint32_t m = l[s];
        l[s] = umin32(key, m);
        key  = umax32(key, m);
    }
}

// ---------------- kernel 1: per-query tau from subsample ----------------
// grid NTOT/64, block 1024 (16 waves). lane = query; wave w chains 64 samples.
__global__ __launch_bounds__(1024, 4) void plap_tau(
    const float* __restrict__ p1, uint32_t* __restrict__ tauG)
{
    __shared__ float sx[SUBS], sy[SUBS], sz[SUBS];     // 12 KB
    __shared__ uint32_t ck[K1 * TW * 64];              // 45056 B

    const int tid  = threadIdx.x;
    const int lane = tid & 63;
    const int wave = tid >> 6;
    const int wq   = __builtin_amdgcn_readfirstlane(wave);
    const int b    = blockIdx.x >> 7;
    const int qi   = ((blockIdx.x & 127) << 6) | lane;
    const float* __restrict__ P = p1 + (size_t)b * NQ * 3;

    // stage subsample points (j = 8t)
    {
        const int t = tid;                              // 0..1023
        const float* src = P + (size_t)(t * SSTRIDE) * 3;
        sx[t] = src[0]; sy[t] = src[1]; sz[t] = src[2];
    }
    const float qx = P[qi * 3 + 0];
    const float qy = P[qi * 3 + 1];
    const float qz = P[qi * 3 + 2];
    __syncthreads();

    uint32_t l[K1];
#pragma unroll
    for (int s = 0; s < K1; ++s) l[s] = 0xFFFFFFFFu;
    const int t0 = wq * (SUBS / TW);                    // 64 samples per wave
#pragma unroll 4
    for (int t = t0; t < t0 + SUBS / TW; ++t) {
        const float dx = qx - sx[t], dy = qy - sy[t], dz = qz - sz[t];  // broadcast
        const float d  = fmaf(dx, dx, fmaf(dy, dy, dz * dz));
        insert11(l, (__float_as_uint(d) & ~IDXMASK) | (uint32_t)(t * SSTRIDE));
    }
#pragma unroll
    for (int s = 0; s < K1; ++s) ck[CKI(s, wq, lane)] = l[s];
    __syncthreads();

    for (int st = 1; st < TW; st <<= 1) {               // tree-merge -> 11th of 1024
        if ((wq & (2 * st - 1)) == 0) {
            uint32_t A[K1];
#pragma unroll
            for (int s = 0; s < K1; ++s) A[s] = ck[CKI(s, wq, lane)];
#pragma unroll
            for (int e = 0; e < K1; ++e) insert11(A, ck[CKI(e, wq + st, lane)]);
            if (2 * st < TW) {
#pragma unroll
                for (int s = 0; s < K1; ++s) ck[CKI(s, wq, lane)] = A[s];
            } else {
                tauG[blockIdx.x * 64 + lane] = A[K1 - 1];
            }
        }
        __syncthreads();
    }
}

// ---------------- kernel 2: filtered scan, LDS-staged candidates ----------------
// grid NTOT/64*HB, block 512 (8 waves). lane = query; wave-uniform candidate stream
// broadcast from LDS; passers appended to per-query LDS lists via atomics.
__global__ __launch_bounds__(512, 8) void plap_scan(
    const float* __restrict__ p1, const uint32_t* __restrict__ tauG,
    uint32_t* __restrict__ keysG, uint32_t* __restrict__ cntG)
{
    __shared__ float sxy[2 * TILE];                    // 8 KB
    __shared__ float sz[TILE];                         // 4 KB
    __shared__ uint32_t lists[64 * LSTR];              // 20736 B
    __shared__ uint32_t cnt[64];                       // 256 B  -> ~33.2 KB total

    const int tid   = threadIdx.x;
    const int lane  = tid & 63;
    const int wave  = tid >> 6;
    const int wq    = __builtin_amdgcn_readfirstlane(wave);
    const int group = blockIdx.x >> 2;                 // 0..255
    const int hb    = blockIdx.x & 3;
    const int b     = group >> 7;
    const int qi    = ((group & 127) << 6) | lane;
    const int qidG  = group * 64 + lane;
    const float* __restrict__ P = p1 + (size_t)b * NQ * 3;

    const float qx = P[qi * 3 + 0];
    const float qy = P[qi * 3 + 1];
    const float qz = P[qi * 3 + 2];
    const uint32_t tq = tauG[qidG];

    if (tid < 64) cnt[tid] = 0;

    const int j0 = hb * CPB;
    for (int tile = 0; tile < CPB / TILE; ++tile) {
        const int jt = j0 + tile * TILE;
        __syncthreads();                                // cnt init / prev tile done
#pragma unroll
        for (int c = tid; c < TILE; c += 512) {         // stage 1024 candidates
            const float* src = P + (size_t)(jt + c) * 3;
            sxy[2 * c]     = src[0];
            sxy[2 * c + 1] = src[1];
            sz[c]          = src[2];
        }
        __syncthreads();

        const int c0 = wq * CPWT;
#pragma unroll 8
        for (int t = 0; t < CPWT; ++t) {
            const int c = c0 + t;
            const float dx = qx - sxy[2 * c];           // uniform addr -> broadcast
            const float dy = qy - sxy[2 * c + 1];
            const float dz = qz - sz[c];
            const float d  = fmaf(dx, dx, fmaf(dy, dy, dz * dz));
            const uint32_t key = (__float_as_uint(d) & ~IDXMASK) | (uint32_t)(jt + c);
            if (key <= tq) {                            // key-space: exact superset
                const uint32_t old = atomicAdd(&cnt[lane], 1u);
                if (old < CAPQ) lists[lane * LSTR + old] = key;
            }
        }
    }
    __syncthreads();

    // write-out: counts (lane-coalesced) + up to CAPQ keys, slot-major coalesced
    if (tid < 64) cntG[(size_t)qidG * HB + hb] = cnt[tid];
    const uint32_t mycnt = umin32(cnt[lane], CAPQ);
    for (int s = wq; s < (int)mycnt; s += WPB)
        keysG[((size_t)hb * CAPQ + s) * NTOT + qidG] = lists[lane * LSTR + s];
}

// ---------------- kernel 3: merge lists -> exact top-11 -> Laplacian L1 loss ----------------
__global__ __launch_bounds__(256) void plap_merge_loss(
    const float* __restrict__ p1, const float* __restrict__ p2,
    const uint32_t* __restrict__ keysG, const uint32_t* __restrict__ cntG,
    float* __restrict__ out)
{
    const int qid = blockIdx.x * 256 + threadIdx.x;    // 0..NTOT-1
    const int b   = qid >> 13;
    const int qi  = qid & (NQ - 1);
    const float* __restrict__ P1 = p1 + (size_t)b * NQ * 3;
    const float* __restrict__ P2 = p2 + (size_t)b * NQ * 3;

    uint32_t F[K1];
#pragma unroll
    for (int s = 0; s < K1; ++s) F[s] = 0xFFFFFFFFu;

    const uint4 c4 = *(const uint4*)&cntG[(size_t)qid * HB];
    const uint32_t cs[HB] = {c4.x, c4.y, c4.z, c4.w};
    bool bad = false;
#pragma unroll
    for (int h = 0; h < HB; ++h) bad |= (cs[h] > CAPQ);

    if (!bad) {
#pragma unroll
        for (int h = 0; h < HB; ++h)
            for (uint32_t s = 0; s < cs[h]; ++s)
                insert11(F, keysG[((size_t)h * CAPQ + s) * NTOT + qid]);
    } else {
        // exact fallback (probability ~0): brute-force rescan of all candidates
        for (int j = 0; j < NQ; ++j) {
            const float dx = P1[qi * 3 + 0] - P1[j * 3 + 0];
            const float dy = P1[qi * 3 + 1] - P1[j * 3 + 1];
            const float dz = P1[qi * 3 + 2] - P1[j * 3 + 2];
            const float d  = fmaf(dx, dx, fmaf(dy, dy, dz * dz));
            insert11(F, (__float_as_uint(d) & ~IDXMASK) | (uint32_t)j);
        }
    }

    float s1x = 0.f, s1y = 0.f, s1z = 0.f, s2x = 0.f, s2y = 0.f, s2z = 0.f;
#pragma unroll
    for (int s = 1; s < K1; ++s) {                     // F[0] = self (d = 0)
        const int n = (int)(F[s] & IDXMASK);
        s1x += P1[n * 3 + 0]; s1y += P1[n * 3 + 1]; s1z += P1[n * 3 + 2];
        s2x += P2[n * 3 + 0]; s2y += P2[n * 3 + 1]; s2z += P2[n * 3 + 2];
    }
    const float invk = 1.0f / (float)KNN;
    const float lx = (s1x * invk - P1[qi * 3 + 0]) - (s2x * invk - P2[qi * 3 + 0]);
    const float ly = (s1y * invk - P1[qi * 3 + 1]) - (s2y * invk - P2[qi * 3 + 1]);
    const float lz = (s1z * invk - P1[qi * 3 + 2]) - (s2z * invk - P2[qi * 3 + 2]);
    float acc = fabsf(lx) + fabsf(ly) + fabsf(lz);

#pragma unroll
    for (int off = 32; off > 0; off >>= 1)
        acc += __shfl_down(acc, off, 64);
    if ((threadIdx.x & 63) == 0)
        atomicAdd(out, acc * (1.0f / (float)(NTOT * 3)));
}

extern "C" void kernel_launch(void* const* d_in, const int* in_sizes, int n_in,
                              void* d_out, int out_size, void* d_ws, size_t ws_size,
                              hipStream_t stream) {
    const float* p1 = (const float*)d_in[0];
    const float* p2 = (const float*)d_in[1];
    float* out      = (float*)d_out;

    // ws: tau (64 KB) | cnt (256 KB) | keys (HB*CAPQ*NTOT*4 = 21.0 MB)
    uint32_t* tauG  = (uint32_t*)d_ws;
    uint32_t* cntG  = tauG + NTOT;
    uint32_t* keysG = cntG + (size_t)NTOT * HB;

    hipMemsetAsync(d_out, 0, sizeof(float), stream);
    plap_tau <<<dim3(NTOT / 64), dim3(TW * 64), 0, stream>>>(p1, tauG);
    plap_scan<<<dim3(NTOT / 64 * HB), dim3(WPB * 64), 0, stream>>>(p1, tauG, keysG, cntG);
    plap_merge_loss<<<dim3(NTOT / 256), dim3(256), 0, stream>>>(p1, p2, keysG, cntG, out);
}

// Round 9
// 145.840 us; speedup vs baseline: 1.3066x; 1.3066x over previous
//
#include <hip/hip_runtime.h>
#include <stdint.h>

#define NQ   8192
#define NB   2
#define KNN  10
#define K1   11                 // top-11 incl. self (dist 0 = global min key); dropped at end
#define NTOT (NB * NQ)
#define IDXMASK 0x1FFFu

// tau kernel: per query, 11th-smallest key over a fixed 1024-point subsample (stride 8)
#define SUBS   1024
#define SSTRIDE 8
#define TW     16               // waves in tau block (1024 threads, 64 queries)
#define CKI(s, c, lane) (((s) * TW + (c)) * 64 + (lane))

// scan kernel: group of 64 queries x 4 blocks; each block scans 2048 candidates
#define HB    4                 // blocks per query-group
#define CPB   (NQ / HB)         // 2048 candidates per block
#define TILE  1024              // candidates staged in LDS per tile
#define WPB   8                 // waves per scan block (512 threads)
#define CPWT  (TILE / WPB)      // 128 candidates per wave per tile
#define CAPQ  80                // list capacity per (query, block); mean occupancy ~22
#define LSTR  81                // LDS list stride (breaks same-bank appends)

static __device__ __forceinline__ uint32_t umin32(uint32_t a, uint32_t b) { return a < b ? a : b; }
static __device__ __forceinline__ uint32_t umax32(uint32_t a, uint32_t b) { return a > b ? a : b; }

static __device__ __forceinline__ void insert11(uint32_t (&l)[K1], uint32_t key) {
#pragma unroll
    for (int s = 0; s < K1; ++s) {
        const uint32_t m = l[s];
        l[s] = umin32(key, m);
        key  = umax32(key, m);
    }
}

// ---------------- kernel 1: per-query tau from subsample ----------------
__global__ __launch_bounds__(1024, 4) void plap_tau(
    const float* __restrict__ p1, uint32_t* __restrict__ tauG)
{
    __shared__ float sx[SUBS], sy[SUBS], sz[SUBS];     // 12 KB
    __shared__ uint32_t ck[K1 * TW * 64];              // 45056 B

    const int tid  = threadIdx.x;
    const int lane = tid & 63;
    const int wave = tid >> 6;
    const int wq   = __builtin_amdgcn_readfirstlane(wave);
    const int b    = blockIdx.x >> 7;
    const int qi   = ((blockIdx.x & 127) << 6) | lane;
    const float* __restrict__ P = p1 + (size_t)b * NQ * 3;

    {
        const int t = tid;                              // 0..1023
        const float* src = P + (size_t)(t * SSTRIDE) * 3;
        sx[t] = src[0]; sy[t] = src[1]; sz[t] = src[2];
    }
    const float qx = P[qi * 3 + 0];
    const float qy = P[qi * 3 + 1];
    const float qz = P[qi * 3 + 2];
    __syncthreads();

    uint32_t l[K1];
#pragma unroll
    for (int s = 0; s < K1; ++s) l[s] = 0xFFFFFFFFu;
    const int t0 = wq * (SUBS / TW);                    // 64 samples per wave
#pragma unroll 4
    for (int t = t0; t < t0 + SUBS / TW; ++t) {
        const float dx = qx - sx[t], dy = qy - sy[t], dz = qz - sz[t];  // broadcast
        const float d  = fmaf(dx, dx, fmaf(dy, dy, dz * dz));
        insert11(l, (__float_as_uint(d) & ~IDXMASK) | (uint32_t)(t * SSTRIDE));
    }
#pragma unroll
    for (int s = 0; s < K1; ++s) ck[CKI(s, wq, lane)] = l[s];
    __syncthreads();

    for (int st = 1; st < TW; st <<= 1) {               // tree-merge -> 11th of 1024
        if ((wq & (2 * st - 1)) == 0) {
            uint32_t A[K1];
#pragma unroll
            for (int s = 0; s < K1; ++s) A[s] = ck[CKI(s, wq, lane)];
#pragma unroll
            for (int e = 0; e < K1; ++e) insert11(A, ck[CKI(e, wq + st, lane)]);
            if (2 * st < TW) {
#pragma unroll
                for (int s = 0; s < K1; ++s) ck[CKI(s, wq, lane)] = A[s];
            } else {
                tauG[blockIdx.x * 64 + lane] = A[K1 - 1];
            }
        }
        __syncthreads();
    }
}

// ---------------- kernel 2: filtered scan, LDS-staged candidates ----------------
__global__ __launch_bounds__(512, 8) void plap_scan(
    const float* __restrict__ p1, const uint32_t* __restrict__ tauG,
    uint32_t* __restrict__ keysG, uint32_t* __restrict__ cntG)
{
    __shared__ float sxy[2 * TILE];                    // 8 KB
    __shared__ float sz[TILE];                         // 4 KB
    __shared__ uint32_t lists[64 * LSTR];              // 20736 B
    __shared__ uint32_t cnt[64];                       // 256 B  -> ~33.2 KB total

    const int tid   = threadIdx.x;
    const int lane  = tid & 63;
    const int wave  = tid >> 6;
    const int wq    = __builtin_amdgcn_readfirstlane(wave);
    const int group = blockIdx.x >> 2;                 // 0..255
    const int hb    = blockIdx.x & 3;
    const int b     = group >> 7;
    const int qi    = ((group & 127) << 6) | lane;
    const int qidG  = group * 64 + lane;
    const float* __restrict__ P = p1 + (size_t)b * NQ * 3;

    const float qx = P[qi * 3 + 0];
    const float qy = P[qi * 3 + 1];
    const float qz = P[qi * 3 + 2];
    const uint32_t tq = tauG[qidG];

    if (tid < 64) cnt[tid] = 0;

    const int j0 = hb * CPB;
    for (int tile = 0; tile < CPB / TILE; ++tile) {
        const int jt = j0 + tile * TILE;
        __syncthreads();                                // cnt init / prev tile done
#pragma unroll
        for (int c = tid; c < TILE; c += 512) {         // stage 1024 candidates
            const float* src = P + (size_t)(jt + c) * 3;
            sxy[2 * c]     = src[0];
            sxy[2 * c + 1] = src[1];
            sz[c]          = src[2];
        }
        __syncthreads();

        const int c0 = wq * CPWT;
#pragma unroll 8
        for (int t = 0; t < CPWT; ++t) {
            const int c = c0 + t;
            const float dx = qx - sxy[2 * c];           // uniform addr -> broadcast
            const float dy = qy - sxy[2 * c + 1];
            const float dz = qz - sz[c];
            const float d  = fmaf(dx, dx, fmaf(dy, dy, dz * dz));
            const uint32_t key = (__float_as_uint(d) & ~IDXMASK) | (uint32_t)(jt + c);
            if (key <= tq) {                            // key-space: exact superset
                const uint32_t old = atomicAdd(&cnt[lane], 1u);
                if (old < CAPQ) lists[lane * LSTR + old] = key;
            }
        }
    }
    __syncthreads();

    if (tid < 64) cntG[(size_t)qidG * HB + hb] = cnt[tid];
    const uint32_t mycnt = umin32(cnt[lane], CAPQ);
    for (int s = wq; s < (int)mycnt; s += WPB)
        keysG[((size_t)hb * CAPQ + s) * NTOT + qidG] = lists[lane * LSTR + s];
}

// ---------------- kernel 3: parallel merge (4 waves/64 queries) + loss ----------------
// block 256 = 64 queries x 4 waves; wave w merges partial-list h=w (coalesced),
// then 2-level LDS tree merge; wave 0 gathers neighbors and accumulates the loss.
__global__ __launch_bounds__(256) void plap_merge_loss(
    const float* __restrict__ p1, const float* __restrict__ p2,
    const uint32_t* __restrict__ keysG, const uint32_t* __restrict__ cntG,
    float* __restrict__ out)
{
    __shared__ uint32_t sk[HB * K1 * 64];              // 11264 B, lane-major
    const int ql = threadIdx.x & 63;
    const int w  = threadIdx.x >> 6;                   // 0..3 == h
    const int wu = __builtin_amdgcn_readfirstlane(w);
    const int qid = blockIdx.x * 64 + ql;              // 0..NTOT-1
    const int b   = qid >> 13;
    const int qi  = qid & (NQ - 1);
    const float* __restrict__ P1 = p1 + (size_t)b * NQ * 3;
    const float* __restrict__ P2 = p2 + (size_t)b * NQ * 3;

    const float qx = P1[qi * 3 + 0];
    const float qy = P1[qi * 3 + 1];
    const float qz = P1[qi * 3 + 2];

    uint32_t F[K1];
#pragma unroll
    for (int s = 0; s < K1; ++s) F[s] = 0xFFFFFFFFu;

    const uint32_t c = cntG[(size_t)qid * HB + wu];
    if (c <= CAPQ) {
        for (uint32_t s = 0; s < c; ++s)               // coalesced: lanes = consecutive qid
            insert11(F, keysG[((size_t)wu * CAPQ + s) * NTOT + qid]);
    } else {
        // exact wave-local fallback (probability ~0): rescan this quarter
        for (int j = wu * CPB; j < (wu + 1) * CPB; ++j) {
            const float dx = qx - P1[j * 3 + 0];
            const float dy = qy - P1[j * 3 + 1];
            const float dz = qz - P1[j * 3 + 2];
            const float d  = fmaf(dx, dx, fmaf(dy, dy, dz * dz));
            insert11(F, (__float_as_uint(d) & ~IDXMASK) | (uint32_t)j);
        }
    }

#pragma unroll
    for (int s = 0; s < K1; ++s) sk[(wu * K1 + s) * 64 + ql] = F[s];
    for (int st = 1; st < HB; st <<= 1) {
        __syncthreads();
        if ((wu & (2 * st - 1)) == 0) {
#pragma unroll
            for (int e = 0; e < K1; ++e) insert11(F, sk[((wu + st) * K1 + e) * 64 + ql]);
            if (2 * st < HB) {
#pragma unroll
                for (int s = 0; s < K1; ++s) sk[(wu * K1 + s) * 64 + ql] = F[s];
            }
        }
    }

    if (wu == 0) {
        float s1x = 0.f, s1y = 0.f, s1z = 0.f, s2x = 0.f, s2y = 0.f, s2z = 0.f;
#pragma unroll
        for (int s = 1; s < K1; ++s) {                 // F[0] = self (d = 0)
            const int n = (int)(F[s] & IDXMASK);
            s1x += P1[n * 3 + 0]; s1y += P1[n * 3 + 1]; s1z += P1[n * 3 + 2];
            s2x += P2[n * 3 + 0]; s2y += P2[n * 3 + 1]; s2z += P2[n * 3 + 2];
        }
        const float invk = 1.0f / (float)KNN;
        const float lx = (s1x * invk - qx) - (s2x * invk - P2[qi * 3 + 0]);
        const float ly = (s1y * invk - qy) - (s2y * invk - P2[qi * 3 + 1]);
        const float lz = (s1z * invk - qz) - (s2z * invk - P2[qi * 3 + 2]);
        float acc = fabsf(lx) + fabsf(ly) + fabsf(lz);
#pragma unroll
        for (int off = 32; off > 0; off >>= 1)
            acc += __shfl_down(acc, off, 64);
        if (ql == 0) atomicAdd(out, acc * (1.0f / (float)(NTOT * 3)));
    }
}

extern "C" void kernel_launch(void* const* d_in, const int* in_sizes, int n_in,
                              void* d_out, int out_size, void* d_ws, size_t ws_size,
                              hipStream_t stream) {
    const float* p1 = (const float*)d_in[0];
    const float* p2 = (const float*)d_in[1];
    float* out      = (float*)d_out;

    // ws: tau (64 KB) | cnt (256 KB) | keys (HB*CAPQ*NTOT*4 = 21.0 MB)
    uint32_t* tauG  = (uint32_t*)d_ws;
    uint32_t* cntG  = tauG + NTOT;
    uint32_t* keysG = cntG + (size_t)NTOT * HB;

    hipMemsetAsync(d_out, 0, sizeof(float), stream);
    plap_tau <<<dim3(NTOT / 64), dim3(TW * 64), 0, stream>>>(p1, tauG);
    plap_scan<<<dim3(NTOT / 64 * HB), dim3(WPB * 64), 0, stream>>>(p1, tauG, keysG, cntG);
    plap_merge_loss<<<dim3(NTOT / 64), dim3(256), 0, stream>>>(p1, p2, keysG, cntG, out);
}